// Round 3
// baseline (87.912 us; speedup 1.0000x reference)
//
#include <hip/hip_runtime.h>

// Quantum circuit sim: 12 wires, DIM=4096, 3 layers, batch=512.
// R3: 512 threads/block (8 waves) for 4 waves/SIMD TLP (grid is fixed at 512
// blocks = 2 blocks/CU; R2's 256-thread blocks left only 2 waves/SIMD and
// ~60% stall time). Each thread owns 8 complex amps; 12 gates/layer applied
// as 4 groups of 3 in-register gates. LDS (padded float2, addr=i+(i>>4),
// conflict-minimal for every phase) remaps between groups. CNOT chain folds
// to the Gray-code map perm(i)=i^(i>>1), applied as gather addresses at each
// layer boundary; final perm folds into measurement weights via inverse-Gray.

namespace {

constexpr int N_WIRES  = 12;
constexpr int DIM      = 1 << N_WIRES;        // 4096
constexpr int N_LAYERS = 3;
constexpr int THREADS  = 512;
constexpr int PER      = DIM / THREADS;       // 8 amps/thread
constexpr int NGATES   = N_LAYERS * N_WIRES;  // 36
constexpr int PADDED   = DIM + (DIM >> 4);    // 4352 float2 slots

__device__ __forceinline__ int pad(int i) { return i + (i >> 4); }

// Apply 3 in-register gates; gate g targets k-bit (2-g).
__device__ __forceinline__ void apply3(float ar[PER], float ai[PER],
                                       const float (*Um)[8], int gbase)
{
    #pragma unroll
    for (int gg = 0; gg < 3; ++gg) {
        const float4 uA = *reinterpret_cast<const float4*>(&Um[gbase + gg][0]);
        const float4 uB = *reinterpret_cast<const float4*>(&Um[gbase + gg][4]);
        const float u00r = uA.x, u00i = uA.y, u01r = uA.z, u01i = uA.w;
        const float u10r = uB.x, u10i = uB.y, u11r = uB.z, u11i = uB.w;
        const int st = 4 >> gg;
        #pragma unroll
        for (int k0 = 0; k0 < PER; ++k0) {
            if (k0 & st) continue;             // static under full unroll
            const int k1 = k0 | st;
            const float r0 = ar[k0], m0 = ai[k0];
            const float r1 = ar[k1], m1 = ai[k1];
            ar[k0] = u00r * r0 - u00i * m0 + u01r * r1 - u01i * m1;
            ai[k0] = u00r * m0 + u00i * r0 + u01r * m1 + u01i * r1;
            ar[k1] = u10r * r0 - u10i * m0 + u11r * r1 - u11i * m1;
            ai[k1] = u10r * m0 + u10i * r0 + u11r * m1 + u11i * r1;
        }
    }
}

__global__ __launch_bounds__(THREADS, 4)
void qcirc_kernel(const float* __restrict__ state,
                  const float* __restrict__ weights,
                  const float* __restrict__ head_w,
                  const float* __restrict__ head_b,
                  float* __restrict__ out)
{
    __shared__ float2 buf[PADDED];
    __shared__ __align__(16) float Umat[NGATES][8];
    __shared__ float redbuf[THREADS / 64];

    const int t = threadIdx.x;                // 9 bits
    const int b = blockIdx.x;

    // ---- 36 gate matrices, one thread each. U = RZ(c)RY(b)RX(a),
    // SU(2): U = [[u00, -conj(u10)], [u10, conj(u00)]].
    if (t < NGATES) {
        const float* wp = weights + t * 3;
        float ha = 0.5f * wp[0], hb = 0.5f * wp[1], hc = 0.5f * wp[2];
        float ca = cosf(ha), sa = sinf(ha);
        float cb = cosf(hb), sb = sinf(hb);
        float ecr = cosf(hc), eci = -sinf(hc);   // e^{-i c/2}
        float t0 = cb * ca, t1 = sb * sa, t2 = sb * ca, t3 = cb * sa;
        float u00r =  ecr * t0 - eci * t1;
        float u00i =  ecr * t1 + eci * t0;
        float u10r =  ecr * t2 - eci * t3;
        float u10i = -ecr * t3 - eci * t2;
        Umat[t][0] =  u00r;  Umat[t][1] =  u00i;
        Umat[t][2] = -u10r;  Umat[t][3] =  u10i;   // U01 = -conj(U10)
        Umat[t][4] =  u10r;  Umat[t][5] =  u10i;
        Umat[t][6] =  u00r;  Umat[t][7] = -u00i;   // U11 = conj(U00)
    }

    // ---- Initial load, P0 layout: i = (k<<9)|t  (coalesced, stride 512).
    float ar[PER], ai[PER];
    {
        const float* sp = state + (size_t)b * DIM;
        #pragma unroll
        for (int k = 0; k < PER; ++k) {
            ar[k] = sp[(k << 9) | t];
            ai[k] = 0.f;
        }
    }
    __syncthreads();   // Umat ready

    #pragma unroll 1
    for (int l = 0; l < N_LAYERS; ++l) {
        const int gb = l * 12;
        if (l > 0) {
            // Gather through fused CNOT perm into P0 layout:
            // new[i] = old[i ^ (i>>1)]  (binary->Gray).
            #pragma unroll
            for (int k = 0; k < PER; ++k) {
                int i = (k << 9) | t;
                int j = i ^ (i >> 1);
                float2 v = buf[pad(j)];
                ar[k] = v.x; ai[k] = v.y;
            }
            __syncthreads();   // all gather-reads done before P0 writes
        }

        // P0: wires 0-2 (i bits 11-9 = k)
        apply3(ar, ai, Umat, gb + 0);
        #pragma unroll
        for (int k = 0; k < PER; ++k) {
            int i = (k << 9) | t;
            buf[pad(i)] = make_float2(ar[k], ai[k]);
        }
        __syncthreads();

        // P1: wires 3-5 (i bits 8-6 = k)
        #pragma unroll
        for (int k = 0; k < PER; ++k) {
            int i = ((t >> 6) << 9) | (k << 6) | (t & 63);
            float2 v = buf[pad(i)];
            ar[k] = v.x; ai[k] = v.y;
        }
        apply3(ar, ai, Umat, gb + 3);
        #pragma unroll
        for (int k = 0; k < PER; ++k) {          // same addrs as read -> no race
            int i = ((t >> 6) << 9) | (k << 6) | (t & 63);
            buf[pad(i)] = make_float2(ar[k], ai[k]);
        }
        __syncthreads();

        // P2: wires 6-8 (i bits 5-3 = k)
        #pragma unroll
        for (int k = 0; k < PER; ++k) {
            int i = ((t >> 3) << 6) | (k << 3) | (t & 7);
            float2 v = buf[pad(i)];
            ar[k] = v.x; ai[k] = v.y;
        }
        apply3(ar, ai, Umat, gb + 6);
        #pragma unroll
        for (int k = 0; k < PER; ++k) {
            int i = ((t >> 3) << 6) | (k << 3) | (t & 7);
            buf[pad(i)] = make_float2(ar[k], ai[k]);
        }
        __syncthreads();

        // P3: wires 9-11 (i bits 2-0 = k)
        #pragma unroll
        for (int k = 0; k < PER; ++k) {
            int i = (t << 3) | k;
            float2 v = buf[pad(i)];
            ar[k] = v.x; ai[k] = v.y;
        }
        apply3(ar, ai, Umat, gb + 9);
        if (l < N_LAYERS - 1) {
            #pragma unroll
            for (int k = 0; k < PER; ++k) {
                int i = (t << 3) | k;
                buf[pad(i)] = make_float2(ar[k], ai[k]);
            }
            __syncthreads();
        }
    }

    // ---- Measurement. Registers hold pre-perm state at j = (t<<3)|k;
    // logical index m = invGray12(j). m>>3 = invGray9(t);
    // m[2:0] = invGray3(k) ^ (parity(t) ? 7 : 0).
    // Weight c_m = sum_w head_w[w] * (1 - 2*bit_{11-w}(m)).
    float hw[N_WIRES];
    #pragma unroll
    for (int w = 0; w < N_WIRES; ++w) hw[w] = head_w[w];

    int it = t ^ (t >> 1); it ^= it >> 2; it ^= it >> 4; it ^= it >> 8; // invGray9(t)
    float chi = 0.f;
    #pragma unroll
    for (int w = 0; w < 9; ++w)                  // wires 0..8 <-> m bits 11..3 = it bits 8..0
        chi += ((it >> (8 - w)) & 1) ? -hw[w] : hw[w];
    const int parfill = (__popc(t) & 1) ? 7 : 0;

    float acc = 0.f;
    #pragma unroll
    for (int k = 0; k < PER; ++k) {
        int ml = (k ^ (k >> 1) ^ (k >> 2)) ^ parfill;   // m[2:0]
        float c = chi;
        c += ((ml >> 2) & 1) ? -hw[9]  : hw[9];
        c += ((ml >> 1) & 1) ? -hw[10] : hw[10];
        c += ( ml       & 1) ? -hw[11] : hw[11];
        float p = ar[k] * ar[k] + ai[k] * ai[k];
        acc += p * c;
    }

    #pragma unroll
    for (int off = 32; off > 0; off >>= 1)
        acc += __shfl_down(acc, off, 64);
    if ((t & 63) == 0) redbuf[t >> 6] = acc;
    __syncthreads();
    if (t == 0) {
        float s = 0.f;
        #pragma unroll
        for (int q = 0; q < THREADS / 64; ++q) s += redbuf[q];
        out[b] = s + head_b[0];
    }
}

} // namespace

extern "C" void kernel_launch(void* const* d_in, const int* in_sizes, int n_in,
                              void* d_out, int out_size, void* d_ws, size_t ws_size,
                              hipStream_t stream)
{
    const float* state   = (const float*)d_in[0];  // (B, 4096) fp32
    const float* weights = (const float*)d_in[1];  // (3, 12, 3) fp32
    const float* head_w  = (const float*)d_in[2];  // (1, 12) fp32
    const float* head_b  = (const float*)d_in[3];  // (1,) fp32
    float* out = (float*)d_out;                    // (B,) fp32

    const int batch = in_sizes[0] / DIM;           // 512
    qcirc_kernel<<<batch, THREADS, 0, stream>>>(state, weights, head_w, head_b, out);
}

// Round 4
// 84.576 us; speedup vs baseline: 1.0394x; 1.0394x over previous
//
#include <hip/hip_runtime.h>

// Quantum circuit sim: 12 wires, DIM=4096, 3 layers, batch=512, fp32.
// R4: instruction-stream diet.
//  - One global LDS layout f(i) = 18*(i>>4) + (i&15): every phase addresses
//    LDS as (one base VGPR) + (compile-time immediate offsets); stride 18
//    float2 = 144 B gives 16-B alignment for b128 pairs and 4-lanes/bank-pair
//    (structural minimum) in every phase, including the Gray gather.
//  - Gate updates written as float2 vector math -> v_pk_fma_f32.
//  - Double-buffered LDS (2 x 36.8 KB, 2 blocks/CU): 9 barriers total.
//  - CNOT chain folded to Gray map perm(i)=i^(i>>1) (gather addresses);
//    final perm folded into measurement weights via inverse-Gray.

namespace {

constexpr int N_WIRES  = 12;
constexpr int DIM      = 1 << N_WIRES;        // 4096
constexpr int THREADS  = 256;
constexpr int PER      = 16;                  // amps per thread
constexpr int NGATES   = 36;
constexpr int PADC     = 4606;                // max f(i) = 288*15+18*15+15 = 4605

__device__ __forceinline__ float2 axpy(float s, float2 v, float2 a) {
    float2 sv = make_float2(s, s);
    return make_float2(sv.x * v.x + a.x, sv.y * v.y + a.y);  // contracts to pk_fma
}
__device__ __forceinline__ float2 scal(float s, float2 v) {
    return make_float2(s * v.x, s * v.y);
}
__device__ __forceinline__ float2 Jrot(float2 v) { return make_float2(-v.y, v.x); }

// 4 in-register gates; gate gg pairs k-bit (3-gg). Umat[g] = {u00,u01,u10,u11}.
__device__ __forceinline__ void apply4(float2 amp[PER],
                                       const float2 (*Um)[4], int gbase)
{
    #pragma unroll
    for (int gg = 0; gg < 4; ++gg) {
        const float2 u00 = Um[gbase + gg][0];
        const float2 u01 = Um[gbase + gg][1];
        const float2 u10 = Um[gbase + gg][2];
        const float2 u11 = Um[gbase + gg][3];
        const int st = 8 >> gg;
        #pragma unroll
        for (int k0 = 0; k0 < PER; ++k0) {
            if (k0 & st) continue;              // static under full unroll
            const int k1 = k0 | st;
            const float2 p = amp[k0], q = amp[k1];
            const float2 jp = Jrot(p), jq = Jrot(q);
            float2 np = scal(u00.x, p);
            np = axpy(u00.y, jp, np);
            np = axpy(u01.x, q,  np);
            np = axpy(u01.y, jq, np);
            float2 nq = scal(u10.x, p);
            nq = axpy(u10.y, jp, nq);
            nq = axpy(u11.x, q,  nq);
            nq = axpy(u11.y, jq, nq);
            amp[k0] = np;
            amp[k1] = nq;
        }
    }
}

__global__ __launch_bounds__(THREADS, 2)
void qcirc_kernel(const float* __restrict__ state,
                  const float* __restrict__ weights,
                  const float* __restrict__ head_w,
                  const float* __restrict__ head_b,
                  float* __restrict__ out)
{
    __shared__ __align__(16) float2 buf[2][PADC];
    __shared__ __align__(16) float2 Umat[NGATES][4];
    __shared__ float redbuf[THREADS / 64];

    const int t = threadIdx.x;                 // 8 bits
    const int b = blockIdx.x;

    // ---- 36 gate matrices. U = RZ(c)RY(b)RX(a); SU(2):
    // U = [[u00, -conj(u10)], [u10, conj(u00)]].
    if (t < NGATES) {
        const float* wp = weights + t * 3;
        float ha = 0.5f * wp[0], hb = 0.5f * wp[1], hc = 0.5f * wp[2];
        float ca = cosf(ha), sa = sinf(ha);
        float cb = cosf(hb), sb = sinf(hb);
        float ecr = cosf(hc), eci = -sinf(hc);   // e^{-i c/2}
        float t0 = cb * ca, t1 = sb * sa, t2 = sb * ca, t3 = cb * sa;
        float u00r =  ecr * t0 - eci * t1;
        float u00i =  ecr * t1 + eci * t0;
        float u10r =  ecr * t2 - eci * t3;
        float u10i = -ecr * t3 - eci * t2;
        Umat[t][0] = make_float2( u00r,  u00i);   // u00
        Umat[t][1] = make_float2(-u10r,  u10i);   // u01 = -conj(u10)
        Umat[t][2] = make_float2( u10r,  u10i);   // u10
        Umat[t][3] = make_float2( u00r, -u00i);   // u11 = conj(u00)
    }

    // ---- Phase bases (f(i) = 18*(i>>4) + (i&15), float2 units).
    const int T  = t >> 4, u = t & 15;
    const int bA = 18 * T + u;                  // A write: i=(k<<8)|t, +288k
    const int bB = 288 * T + 18 * 0 + u;        // B r/w:  i=(T<<8)|(k<<4)|u, +18k
    const int bC = 18 * t;                      // C r/w:  i=(t<<4)|k, +k (b128 pairs)
    const int tb  = t ^ (t >> 1);               // Gray(t), 8-bit
    const int tbx = tb ^ 128;
    const int pb0 = 18 * (tb  >> 4) + (tb  & 15);  // gather base, k even
    const int pb1 = 18 * (tbx >> 4) + (tbx & 15);  // gather base, k odd

    // ---- Initial load, A-layout: amp[k] = state[(k<<8)|t] (coalesced).
    float2 amp[PER];
    {
        const float* sp = state + (size_t)b * DIM;
        #pragma unroll
        for (int k = 0; k < PER; ++k)
            amp[k] = make_float2(sp[(k << 8) | t], 0.f);
    }
    __syncthreads();   // Umat ready

    #pragma unroll
    for (int l = 0; l < 3; ++l) {
        const int gb = l * 12;
        if (l > 0) {
            // Gather through CNOT perm into A-layout:
            // new[(k<<8)|t] = old[j], j = (gray4(k)<<8) | (gray8(t) ^ ((k&1)<<7)).
            const float2* src = buf[(3 * l - 1) & 1];
            #pragma unroll
            for (int k = 0; k < PER; ++k) {
                const int g = k ^ (k >> 1);                 // gray4(k), static
                amp[k] = src[((k & 1) ? pb1 : pb0) + 288 * g];
            }
        }

        // Group A: wires 0-3 (i bits 11-8 = k)
        apply4(amp, Umat, gb + 0);
        {
            float2* w = &buf[(3 * l) & 1][bA];
            #pragma unroll
            for (int k = 0; k < PER; ++k) w[288 * k] = amp[k];
        }
        __syncthreads();
        {
            const float2* r = &buf[(3 * l) & 1][bB];
            #pragma unroll
            for (int k = 0; k < PER; ++k) amp[k] = r[18 * k];
        }

        // Group B: wires 4-7 (i bits 7-4 = k)
        apply4(amp, Umat, gb + 4);
        {
            float2* w = &buf[(3 * l + 1) & 1][bB];
            #pragma unroll
            for (int k = 0; k < PER; ++k) w[18 * k] = amp[k];
        }
        __syncthreads();
        {
            const float4* r = reinterpret_cast<const float4*>(&buf[(3 * l + 1) & 1][bC]);
            #pragma unroll
            for (int k = 0; k < PER / 2; ++k) {
                float4 v = r[k];
                amp[2 * k]     = make_float2(v.x, v.y);
                amp[2 * k + 1] = make_float2(v.z, v.w);
            }
        }

        // Group C: wires 8-11 (i bits 3-0 = k)
        apply4(amp, Umat, gb + 8);
        if (l < 2) {
            float4* w = reinterpret_cast<float4*>(&buf[(3 * l + 2) & 1][bC]);
            #pragma unroll
            for (int k = 0; k < PER / 2; ++k)
                w[k] = make_float4(amp[2 * k].x, amp[2 * k].y,
                                   amp[2 * k + 1].x, amp[2 * k + 1].y);
            __syncthreads();
        }
    }

    // ---- Measurement. Regs hold pre-perm state at j = (t<<4)|k; logical
    // m = invGray12(j): m[11:4] = invGray8(t), m[3:0] = invGray4(k) ^ (par(t)*0xF).
    float hw[N_WIRES];
    #pragma unroll
    for (int w = 0; w < N_WIRES; ++w) hw[w] = head_w[w];

    int it = t ^ (t >> 1); it ^= it >> 2; it ^= it >> 4;   // invGray8(t)
    float chi = 0.f;
    #pragma unroll
    for (int w = 0; w < 8; ++w)
        chi += ((it >> (7 - w)) & 1) ? -hw[w] : hw[w];
    const int parfill = (__popc(t) & 1) ? 0xF : 0;

    float acc = 0.f;
    #pragma unroll
    for (int k = 0; k < PER; ++k) {
        int ml = (k ^ (k >> 1)); ml ^= ml >> 2; ml ^= parfill;  // m[3:0]
        float c = chi;
        c += ((ml >> 3) & 1) ? -hw[8]  : hw[8];
        c += ((ml >> 2) & 1) ? -hw[9]  : hw[9];
        c += ((ml >> 1) & 1) ? -hw[10] : hw[10];
        c += ( ml       & 1) ? -hw[11] : hw[11];
        float p = amp[k].x * amp[k].x + amp[k].y * amp[k].y;
        acc += p * c;
    }

    #pragma unroll
    for (int off = 32; off > 0; off >>= 1)
        acc += __shfl_down(acc, off, 64);
    if ((t & 63) == 0) redbuf[t >> 6] = acc;
    __syncthreads();
    if (t == 0) {
        float s = 0.f;
        #pragma unroll
        for (int q = 0; q < THREADS / 64; ++q) s += redbuf[q];
        out[b] = s + head_b[0];
    }
}

} // namespace

extern "C" void kernel_launch(void* const* d_in, const int* in_sizes, int n_in,
                              void* d_out, int out_size, void* d_ws, size_t ws_size,
                              hipStream_t stream)
{
    const float* state   = (const float*)d_in[0];  // (B, 4096) fp32
    const float* weights = (const float*)d_in[1];  // (3, 12, 3) fp32
    const float* head_w  = (const float*)d_in[2];  // (1, 12) fp32
    const float* head_b  = (const float*)d_in[3];  // (1,) fp32
    float* out = (float*)d_out;                    // (B,) fp32

    const int batch = in_sizes[0] / DIM;           // 512
    qcirc_kernel<<<batch, THREADS, 0, stream>>>(state, weights, head_w, head_b, out);
}